// Round 5
// baseline (83.213 us; speedup 1.0000x reference)
//
#include <hip/hip_runtime.h>
#include <cmath>

// out[b,o] = bias[o] + sum_i x[b,i] * (w[i,o] + (|w[i,o]|+1e-15)*noise[b,i,o])
// BS=64, IN_F=1024, OUT_F=1024. Memory-bound on the 256 MiB noise stream.
//
// R4: single fused kernel, grid split over OUTPUT chunks (no partials, no
// second launch). Each block owns (b, 128 outputs): 8 i-groups x 32 o-threads,
// each thread accumulates 4 outputs over its 128-row i-chunk, then a 4KB LDS
// reduction + bias + store. Noise coalescing identical to R1 (512B contiguous
// per 32-lane half-wave); TLP identical (512 blocks). Removes 4.3MB partial
// round-trip + reduce-kernel launch tail.

constexpr int BS      = 64;
constexpr int IN_F    = 1024;
constexpr int OUT_F   = 1024;
constexpr int OCH     = 8;               // output chunks
constexpr int OBLK    = OUT_F / OCH;     // 128 outputs per block
constexpr int IGROUPS = 8;               // i-groups per block
constexpr int ICHUNK  = IN_F / IGROUPS;  // 128 rows per group
constexpr int OTHREADS = OBLK / 4;       // 32 o-threads (4 outputs each)

__global__ __launch_bounds__(256) void bridgeout_fused_osplit(
    const float* __restrict__ x, const float* __restrict__ w,
    const float* __restrict__ bias, const float* __restrict__ noise,
    float* __restrict__ out) {
  const int oc = blockIdx.x;          // output chunk
  const int b  = blockIdx.y;          // batch sample
  const int t  = threadIdx.x;
  const int ig = t >> 5;              // i-group 0..7
  const int ot = t & 31;              // o-thread 0..31
  const int o  = oc * OBLK + (ot << 2);

  __shared__ float  xs[IN_F];                  // 4 KB
  __shared__ float4 red[IGROUPS][OTHREADS];    // 4 KB

  for (int i = t; i < IN_F; i += 256) xs[i] = x[b * IN_F + i];
  __syncthreads();

  const int i0 = ig * ICHUNK;
  const float* wp = w + (size_t)i0 * OUT_F + o;
  const float* np = noise + ((size_t)b * IN_F + i0) * OUT_F + o;

  float ax = 0.f, ay = 0.f, az = 0.f, aw = 0.f;
#pragma unroll 4
  for (int i = 0; i < ICHUNK; ++i) {
    const float xv = xs[i0 + i];
    const float4 w4 = *reinterpret_cast<const float4*>(wp);
    const float4 n4 = *reinterpret_cast<const float4*>(np);
    // w_noisy = w + (|w|+1e-15)*noise ; acc += x * w_noisy
    ax = fmaf(xv, fmaf(fabsf(w4.x) + 1e-15f, n4.x, w4.x), ax);
    ay = fmaf(xv, fmaf(fabsf(w4.y) + 1e-15f, n4.y, w4.y), ay);
    az = fmaf(xv, fmaf(fabsf(w4.z) + 1e-15f, n4.z, w4.z), az);
    aw = fmaf(xv, fmaf(fabsf(w4.w) + 1e-15f, n4.w, w4.w), aw);
    wp += OUT_F;
    np += OUT_F;
  }
  red[ig][ot] = make_float4(ax, ay, az, aw);
  __syncthreads();

  if (ig == 0) {
    float4 a = red[0][ot];
#pragma unroll
    for (int g = 1; g < IGROUPS; ++g) {
      const float4 p = red[g][ot];
      a.x += p.x; a.y += p.y; a.z += p.z; a.w += p.w;
    }
    const float4 bi = *reinterpret_cast<const float4*>(bias + o);
    a.x += bi.x; a.y += bi.y; a.z += bi.z; a.w += bi.w;
    *reinterpret_cast<float4*>(out + (size_t)b * OUT_F + o) = a;
  }
}

extern "C" void kernel_launch(void* const* d_in, const int* in_sizes, int n_in,
                              void* d_out, int out_size, void* d_ws, size_t ws_size,
                              hipStream_t stream) {
  const float* x     = (const float*)d_in[0];
  const float* w     = (const float*)d_in[1];
  const float* bias  = (const float*)d_in[2];
  const float* noise = (const float*)d_in[3];
  float* out = (float*)d_out;
  (void)d_ws; (void)ws_size;

  dim3 grid(OCH, BS);
  bridgeout_fused_osplit<<<grid, 256, 0, stream>>>(x, w, bias, noise, out);
}

// Round 6
// 48.148 us; speedup vs baseline: 1.7283x; 1.7283x over previous
//
#include <hip/hip_runtime.h>
#include <cmath>

// out[b,o] = bias[o] + sum_i x[b,i] * (w[i,o] + (|w[i,o]|+1e-15)*noise[b,i,o])
// BS=64, IN_F=1024, OUT_F=1024. Memory-bound on the 256 MiB noise stream.
//
// R5: base = R3's two-kernel i-split (48.3 us known-good). New: noise chunks
// ic<NT_CHUNKS are loaded nontemporal (no L2/L3 allocation). Cached footprint
// drops from 275 MB (> 256 MB L3, self-evicting) to ~199 MB (< L3) so the
// remaining 6 chunks can stay L3-resident across graph replays.
// Evidence: R3 showed NT-everything costs ~4.7 us => plain loads harvest
// substantial L3 hits; shrinking the cached set should grow them.

constexpr int BS    = 64;
constexpr int IN_F  = 1024;
constexpr int OUT_F = 1024;
constexpr int ICH   = 8;             // i-chunks for extra parallelism
constexpr int CHUNK = IN_F / ICH;    // 128
constexpr int NT_CHUNKS = 2;         // chunks 0,1 (64 MB) bypass cache

typedef float floatx4 __attribute__((ext_vector_type(4)));

// ---- Kernel 1: per-(i-chunk, b) partial sums over 256 threads x 4 o's ----
__global__ __launch_bounds__(256) void bridgeout_partial(
    const float* __restrict__ x, const float* __restrict__ w,
    const float* __restrict__ noise, float* __restrict__ partials) {
  const int ic = blockIdx.x;   // i-chunk
  const int b  = blockIdx.y;   // batch sample
  const int t  = threadIdx.x;
  const int o  = t << 2;       // 4 consecutive outputs per thread

  __shared__ float xs[CHUNK];
  if (t < CHUNK) xs[t] = x[b * IN_F + ic * CHUNK + t];
  __syncthreads();

  const float* wp = w + (size_t)(ic * CHUNK) * OUT_F + o;
  const float* np = noise + ((size_t)b * IN_F + (size_t)(ic * CHUNK)) * OUT_F + o;

  float ax = 0.f, ay = 0.f, az = 0.f, aw = 0.f;
  if (ic < NT_CHUNKS) {
    // sacrificial chunks: nontemporal, keep L3 for the other 6 chunks
#pragma unroll 4
    for (int i = 0; i < CHUNK; ++i) {
      const float xv = xs[i];
      const float4 w4 = *reinterpret_cast<const float4*>(wp);
      const floatx4 n4 = __builtin_nontemporal_load(reinterpret_cast<const floatx4*>(np));
      ax = fmaf(xv, fmaf(fabsf(w4.x) + 1e-15f, n4.x, w4.x), ax);
      ay = fmaf(xv, fmaf(fabsf(w4.y) + 1e-15f, n4.y, w4.y), ay);
      az = fmaf(xv, fmaf(fabsf(w4.z) + 1e-15f, n4.z, w4.z), az);
      aw = fmaf(xv, fmaf(fabsf(w4.w) + 1e-15f, n4.w, w4.w), aw);
      wp += OUT_F;
      np += OUT_F;
    }
  } else {
#pragma unroll 4
    for (int i = 0; i < CHUNK; ++i) {
      const float xv = xs[i];
      const float4 w4 = *reinterpret_cast<const float4*>(wp);
      const float4 n4 = *reinterpret_cast<const float4*>(np);
      ax = fmaf(xv, fmaf(fabsf(w4.x) + 1e-15f, n4.x, w4.x), ax);
      ay = fmaf(xv, fmaf(fabsf(w4.y) + 1e-15f, n4.y, w4.y), ay);
      az = fmaf(xv, fmaf(fabsf(w4.z) + 1e-15f, n4.z, w4.z), az);
      aw = fmaf(xv, fmaf(fabsf(w4.w) + 1e-15f, n4.w, w4.w), aw);
      wp += OUT_F;
      np += OUT_F;
    }
  }
  float4 acc = make_float4(ax, ay, az, aw);
  *reinterpret_cast<float4*>(partials + (size_t)(ic * BS + b) * OUT_F + o) = acc;
}

// ---- Kernel 2: reduce ICH partials + bias -> out (fully overwrites out) ----
__global__ __launch_bounds__(256) void bridgeout_reduce(
    const float* __restrict__ partials, const float* __restrict__ bias,
    float* __restrict__ out) {
  const int idx = blockIdx.x * 256 + threadIdx.x;
  const int e = idx << 2;                 // element index in [0, BS*OUT_F)
  if (e >= BS * OUT_F) return;
  const int b = e >> 10;                  // / OUT_F
  const int o = e & (OUT_F - 1);
  float4 a = *reinterpret_cast<const float4*>(bias + o);
#pragma unroll
  for (int c = 0; c < ICH; ++c) {
    const float4 p = *reinterpret_cast<const float4*>(
        partials + (size_t)(c * BS + b) * OUT_F + o);
    a.x += p.x; a.y += p.y; a.z += p.z; a.w += p.w;
  }
  *reinterpret_cast<float4*>(out + e) = a;
}

// ---- Fallback: fused single-pass (grid = BS), used only if ws too small ----
__global__ __launch_bounds__(256) void bridgeout_fused(
    const float* __restrict__ x, const float* __restrict__ w,
    const float* __restrict__ bias, const float* __restrict__ noise,
    float* __restrict__ out) {
  const int b = blockIdx.x;
  const int t = threadIdx.x;
  const int o = t << 2;

  __shared__ float xs[IN_F];
  for (int i = t; i < IN_F; i += 256) xs[i] = x[b * IN_F + i];
  __syncthreads();

  const float* wp = w + o;
  const float* np = noise + (size_t)b * IN_F * OUT_F + o;
  float ax = 0.f, ay = 0.f, az = 0.f, aw = 0.f;
#pragma unroll 4
  for (int i = 0; i < IN_F; ++i) {
    const float xv = xs[i];
    const float4 w4 = *reinterpret_cast<const float4*>(wp);
    const float4 n4 = *reinterpret_cast<const float4*>(np);
    ax = fmaf(xv, fmaf(fabsf(w4.x) + 1e-15f, n4.x, w4.x), ax);
    ay = fmaf(xv, fmaf(fabsf(w4.y) + 1e-15f, n4.y, w4.y), ay);
    az = fmaf(xv, fmaf(fabsf(w4.z) + 1e-15f, n4.z, w4.z), az);
    aw = fmaf(xv, fmaf(fabsf(w4.w) + 1e-15f, n4.w, w4.w), aw);
    wp += OUT_F;
    np += OUT_F;
  }
  const float4 bi = *reinterpret_cast<const float4*>(bias + o);
  float4 acc = make_float4(ax + bi.x, ay + bi.y, az + bi.z, aw + bi.w);
  *reinterpret_cast<float4*>(out + (size_t)b * OUT_F + o) = acc;
}

extern "C" void kernel_launch(void* const* d_in, const int* in_sizes, int n_in,
                              void* d_out, int out_size, void* d_ws, size_t ws_size,
                              hipStream_t stream) {
  const float* x     = (const float*)d_in[0];
  const float* w     = (const float*)d_in[1];
  const float* bias  = (const float*)d_in[2];
  const float* noise = (const float*)d_in[3];
  float* out = (float*)d_out;

  const size_t need = (size_t)ICH * BS * OUT_F * sizeof(float);  // 2 MiB
  if (ws_size >= need) {
    float* partials = (float*)d_ws;
    dim3 g1(ICH, BS);
    bridgeout_partial<<<g1, 256, 0, stream>>>(x, w, noise, partials);
    const int nthr = BS * OUT_F / 4;                  // 16384 threads
    bridgeout_reduce<<<(nthr + 255) / 256, 256, 0, stream>>>(partials, bias, out);
  } else {
    bridgeout_fused<<<BS, 256, 0, stream>>>(x, w, bias, noise, out);
  }
}